// Round 9
// baseline (182.262 us; speedup 1.0000x reference)
//
#include <hip/hip_runtime.h>

// Problem constants
#define BB 16
#define CC 2048
#define HH 32
#define WW 32
#define HW 1024   // H*W
#define NP 64     // n_points

// prep tiling
#define PCH 32            // c-rows per prep block
#define NCH (CC/PCH)      // 64 chunks

// gemm tiling
#define KB 64             // spatial-k per gemm block (2 k32-tiles)
#define CT 64             // c per K-step
#define BP 68             // LDS k-pitch in u16 (136 B): rows 8 apart -> disjoint bank halves

// ATTRIBUTION ROUND: gemm launched GREP=5 times (idempotent deterministic
// stores) -> gemm_us = (T - T_prev) / (GREP-1) with everything else identical
// to round 8 (T_prev = 64.2 us).
#define GREP 5

typedef __bf16 bf16x8  __attribute__((ext_vector_type(8)));
typedef float  f32x4   __attribute__((ext_vector_type(4)));
typedef float  f32x16  __attribute__((ext_vector_type(16)));

__device__ __forceinline__ unsigned f2bf2(float lo, float hi) {
    // pack two fp32 -> two RNE bf16 in one u32
    unsigned a = __float_as_uint(lo);
    unsigned b = __float_as_uint(hi);
    a += 0x7fffu + ((a >> 16) & 1u);
    b += 0x7fffu + ((b >> 16) & 1u);
    return (a >> 16) | (b & 0xffff0000u);
}

// ws layout:
//   qbf:  [BB][NP][CC] bf16       = 4 MiB  (gathered queries, bf16(fea) columns)
//   np2:  [NCH][BB][HW] f32       = 4 MiB  (partial key sum-of-squares)
//   rn:   [BB][HW] f32            = 64 KiB (rsqrt of key norms^2)
//   dotp: [NCS][BB][NP][HW] f32   = NCS*4 MiB (partial raw dot products)

// ---------------------------------------------------------------------------
// Kernel 1: coalesced fea scan (proven, unchanged).
// ---------------------------------------------------------------------------
__global__ __launch_bounds__(256) void prep_kernel(const float* __restrict__ fea,
                                                   const float* __restrict__ pl,
                                                   unsigned short* __restrict__ qbf,
                                                   float* __restrict__ np2) {
    int cch = blockIdx.x, b = blockIdx.y;
    int t = threadIdx.x, lane = t & 63, rr = t >> 6;

    int ix = (int)(pl[2 * lane + 0] * WW); ix = min(max(ix, 0), WW - 1);
    int iy = (int)(pl[2 * lane + 1] * HH); iy = min(max(iy, 0), HH - 1);
    int kp = iy * WW + ix;

    __shared__ unsigned short buf[2][4][HW];     // 16 KiB double-buffered bf16 rows
    __shared__ unsigned short ex[NP][PCH + 4];   // extracted queries [p][c_local]

    float ssq[16];
#pragma unroll
    for (int i = 0; i < 16; ++i) ssq[i] = 0.f;

    const float* base = fea + ((size_t)b * CC + cch * PCH + rr) * HW + 4 * lane;

#pragma unroll
    for (int ph = 0; ph < PCH / 4; ++ph) {       // 8 phases x 4 rows
        float4 fv[4];
#pragma unroll
        for (int s = 0; s < 4; ++s)
            fv[s] = *(const float4*)(base + (size_t)(ph * 4) * HW + 256 * s);
#pragma unroll
        for (int s = 0; s < 4; ++s) {
            ssq[4 * s + 0] += fv[s].x * fv[s].x;
            ssq[4 * s + 1] += fv[s].y * fv[s].y;
            ssq[4 * s + 2] += fv[s].z * fv[s].z;
            ssq[4 * s + 3] += fv[s].w * fv[s].w;
            uint2 pk;
            pk.x = f2bf2(fv[s].x, fv[s].y);
            pk.y = f2bf2(fv[s].z, fv[s].w);
            *(uint2*)&buf[ph & 1][rr][4 * lane + 256 * s] = pk;
        }
        __syncthreads();
        ex[lane][ph * 4 + rr] = buf[ph & 1][rr][kp];
    }
    __syncthreads();

    float* red = (float*)buf;
#pragma unroll
    for (int s = 0; s < 4; ++s) {
        f32x4 v = {ssq[4 * s + 0], ssq[4 * s + 1], ssq[4 * s + 2], ssq[4 * s + 3]};
        *(f32x4*)&red[rr * HW + 4 * lane + 256 * s] = v;
    }
    __syncthreads();
    {
        int k0 = 4 * t;
        f32x4 r0 = *(f32x4*)&red[0 * HW + k0];
        f32x4 r1 = *(f32x4*)&red[1 * HW + k0];
        f32x4 r2 = *(f32x4*)&red[2 * HW + k0];
        f32x4 r3 = *(f32x4*)&red[3 * HW + k0];
        f32x4 sum = (r0 + r1) + (r2 + r3);
        *(f32x4*)&np2[((size_t)cch * BB + b) * HW + k0] = sum;
    }
    {
        int p = t >> 2, part = t & 3;
        uint2 lo = *(uint2*)&ex[p][8 * part];
        uint2 hi = *(uint2*)&ex[p][8 * part + 4];
        uint4 o = make_uint4(lo.x, lo.y, hi.x, hi.y);
        *(uint4*)&qbf[((size_t)b * NP + p) * CC + cch * PCH + 8 * part] = o;
    }
}

// ---------------------------------------------------------------------------
// Kernel 2: reduce np2 partials -> rn = rsqrt(sum). grid = (8, BB), block 128.
// ---------------------------------------------------------------------------
__global__ __launch_bounds__(128) void nred_kernel(const float* __restrict__ np2,
                                                   float* __restrict__ rn) {
    int b = blockIdx.y;
    int k = blockIdx.x * 128 + threadIdx.x;
    float s = 0.f;
#pragma unroll 8
    for (int cch = 0; cch < NCH; ++cch)
        s += np2[((size_t)cch * BB + b) * HW + k];
    rn[(size_t)b * HW + k] = rsqrtf(s);
}

// ---------------------------------------------------------------------------
// Kernel 3: 32x32x16 bf16 MFMA GEMM, c-split = NCS (2 or 4). Unchanged r8.
// ---------------------------------------------------------------------------
template<int NCS>
__global__ __launch_bounds__(256) void gemm_kernel(const float* __restrict__ fea,
                                                   const unsigned short* __restrict__ qbf,
                                                   float* __restrict__ dotp) {
    constexpr int CHALF = CC / NCS;
    constexpr int NST = CHALF / CT;
    constexpr int CSB = (NCS == 4) ? 2 : 1;      // log2(NCS)

    int id = blockIdx.x + (int)gridDim.x * blockIdx.y;        // 0..256*NCS-1
    int cpx = (16 * NCS * BB) >> 3;
    int sid = (id & 7) * cpx + (id >> 3);                     // XCD-chunked
    int kc = sid & 15;
    int cs = (sid >> 4) & (NCS - 1);
    int b  = sid >> (4 + CSB);

    int t = threadIdx.x, lane = t & 63, w = t >> 6;
    int pt = w >> 1, kt = w & 1;                              // wave -> (p32, k32) tile
    int p0 = 32 * pt;
    int k0 = KB * kc;
    int c0 = cs * CHALF;
    int lo = lane & 31, hi = lane >> 5;

    __shared__ __align__(16) unsigned short bt[2][CT][BP];    // 17 KiB

    // staging: thread -> c-row sc (0..63), 16-k segment sq (0..3)
    int sc = t >> 2, sq = t & 3;
    const float* gsrc = fea + ((size_t)b * CC + c0 + sc) * HW + k0 + 16 * sq;

    // A rows: lane lo -> p0+lo; elems e -> c = s*CT + 16*cw + 8*hi + e
    const unsigned short* qb = qbf + ((size_t)b * NP + p0 + lo) * CC + c0 + 8 * hi;

    f32x16 acc = {};
    union UA { int4 i; bf16x8 v; };

    // preload step 0: staging data + A fragments
    float4 g[4];
#pragma unroll
    for (int h = 0; h < 4; ++h) g[h] = *(const float4*)(gsrc + 4 * h);
    UA a_cur[4], a_nxt[4];
#pragma unroll
    for (int cw = 0; cw < 4; ++cw) a_cur[cw].i = *(const int4*)(qb + 16 * cw);

    for (int s = 0; s < NST; ++s) {
        int cur = s & 1;
        // stage current tile: 4 uint2 writes (k = 16sq+4h..+3 at row sc)
#pragma unroll
        for (int h = 0; h < 4; ++h) {
            uint2 pk;
            pk.x = f2bf2(g[h].x, g[h].y);
            pk.y = f2bf2(g[h].z, g[h].w);
            *(uint2*)&bt[cur][sc][16 * sq + 4 * h] = pk;
        }
        __syncthreads();

        // prefetch next step's staging data + A fragments (fly under compute)
        int sn = (s + 1 < NST) ? s + 1 : s;
#pragma unroll
        for (int h = 0; h < 4; ++h)
            g[h] = *(const float4*)(gsrc + (size_t)sn * CT * HW + 4 * h);
#pragma unroll
        for (int cw = 0; cw < 4; ++cw)
            a_nxt[cw].i = *(const int4*)(qb + (size_t)sn * CT + 16 * cw);

        // compute: 4 MFMA (c-chunks of 16), B-frag = 8 u16 LDS reads each
#pragma unroll
        for (int cw = 0; cw < 4; ++cw) {
            union { unsigned short u[8]; bf16x8 v; } bf;
#pragma unroll
            for (int e = 0; e < 8; ++e)
                bf.u[e] = bt[cur][16 * cw + 8 * hi + e][32 * kt + lo];
            acc = __builtin_amdgcn_mfma_f32_32x32x16_bf16(a_cur[cw].v, bf.v, acc, 0, 0, 0);
        }
#pragma unroll
        for (int cw = 0; cw < 4; ++cw) a_cur[cw] = a_nxt[cw];
    }

    // D layout (32x32): col k = lane&31, row p = (r&3) + 8*(r>>2) + 4*(lane>>5)
    float* dbase = dotp + (((size_t)cs * BB + b) * NP) * HW;
#pragma unroll
    for (int r = 0; r < 16; ++r) {
        int p = p0 + (r & 3) + 8 * (r >> 2) + 4 * hi;
        dbase[(size_t)p * HW + k0 + 32 * kt + lo] = acc[r];
    }
}

// ---------------------------------------------------------------------------
// Kernel 4: finalize. val = (sum of NCS partials) * rn[k] * rn[kp];
// min/max over k; out = valid ? (val - amin)/amax : 0.
// grid = (NP, BB), block = 256.
// ---------------------------------------------------------------------------
template<int NCS>
__global__ __launch_bounds__(256) void finalize_kernel(const float* __restrict__ dotp,
                                                       const float* __restrict__ rn,
                                                       const float* __restrict__ pl,
                                                       const int* __restrict__ valid,
                                                       float* __restrict__ out) {
    int p = blockIdx.x, b = blockIdx.y;
    int t = threadIdx.x;
    int k0 = 4 * t;

    int ix = (int)(pl[2 * p + 0] * WW); ix = min(max(ix, 0), WW - 1);
    int iy = (int)(pl[2 * p + 1] * HH); iy = min(max(iy, 0), HH - 1);
    int kp = iy * WW + ix;
    float rnp = rn[(size_t)b * HW + kp];

    f32x4 d = {0.f, 0.f, 0.f, 0.f};
#pragma unroll
    for (int cs = 0; cs < NCS; ++cs)
        d += *(const f32x4*)(dotp + (((size_t)cs * BB + b) * NP + p) * HW + k0);
    float4 rk = *(const float4*)&rn[(size_t)b * HW + k0];

    float val[4];
    val[0] = d[0] * rk.x * rnp;
    val[1] = d[1] * rk.y * rnp;
    val[2] = d[2] * rk.z * rnp;
    val[3] = d[3] * rk.w * rnp;

    float mn = fminf(fminf(val[0], val[1]), fminf(val[2], val[3]));
    float mx = fmaxf(fmaxf(val[0], val[1]), fmaxf(val[2], val[3]));
#pragma unroll
    for (int off = 32; off; off >>= 1) {
        mn = fminf(mn, __shfl_xor(mn, off));
        mx = fmaxf(mx, __shfl_xor(mx, off));
    }
    __shared__ float smn[4], smx[4];
    int wave = t >> 6;
    if ((t & 63) == 0) { smn[wave] = mn; smx[wave] = mx; }
    __syncthreads();
    mn = fminf(fminf(smn[0], smn[1]), fminf(smn[2], smn[3]));
    mx = fmaxf(fmaxf(smx[0], smx[1]), fmaxf(smx[2], smx[3]));

    bool vld = valid[p] != 0;
    float4 o;
    o.x = vld ? (val[0] - mn) / mx : 0.f;
    o.y = vld ? (val[1] - mn) / mx : 0.f;
    o.z = vld ? (val[2] - mn) / mx : 0.f;
    o.w = vld ? (val[3] - mn) / mx : 0.f;
    *(float4*)&out[((size_t)b * NP + p) * HW + k0] = o;
}

// ---------------------------------------------------------------------------
extern "C" void kernel_launch(void* const* d_in, const int* in_sizes, int n_in,
                              void* d_out, int out_size, void* d_ws, size_t ws_size,
                              hipStream_t stream) {
    const float* fea = (const float*)d_in[0];
    const float* pl  = (const float*)d_in[1];
    const int* valid = (const int*)d_in[2];
    float* out = (float*)d_out;

    unsigned short* qbf = (unsigned short*)d_ws;                 // 4 MiB
    float* np2 = (float*)(qbf + (size_t)BB * NP * CC);           // 4 MiB
    float* rn  = np2 + (size_t)NCH * BB * HW;                    // 64 KiB
    float* dotp = rn + (size_t)BB * HW;                          // NCS*4 MiB

    // bytes needed with NCS=4 partial-dot pages
    const size_t base_b = ((size_t)BB * NP * CC) * 2 + ((size_t)NCH * BB * HW + (size_t)BB * HW) * 4;
    const size_t need4 = base_b + (size_t)4 * BB * NP * HW * 4;

    prep_kernel<<<dim3(NCH, BB), 256, 0, stream>>>(fea, pl, qbf, np2);
    nred_kernel<<<dim3(8, BB), 128, 0, stream>>>(np2, rn);
    if (ws_size >= need4) {
        for (int rep = 0; rep < GREP; ++rep)
            gemm_kernel<4><<<dim3(64, BB), 256, 0, stream>>>(fea, qbf, dotp);
        finalize_kernel<4><<<dim3(NP, BB), 256, 0, stream>>>(dotp, rn, pl, valid, out);
    } else {
        for (int rep = 0; rep < GREP; ++rep)
            gemm_kernel<2><<<dim3(32, BB), 256, 0, stream>>>(fea, qbf, dotp);
        finalize_kernel<2><<<dim3(NP, BB), 256, 0, stream>>>(dotp, rn, pl, valid, out);
    }
}

// Round 10
// 72.216 us; speedup vs baseline: 2.5238x; 2.5238x over previous
//
#include <hip/hip_runtime.h>

// Problem constants
#define BB 16
#define CC 2048
#define HH 32
#define WW 32
#define HW 1024   // H*W
#define NP 64     // n_points

#define NCH 64            // c-slabs of 32 for prep/np2 pages
#define KB 64             // spatial-k per gemm block (2 k32-tiles)
#define CT 64             // c per K-step
#define BP 68             // (fallback LDS pitch)

typedef __bf16 bf16x8  __attribute__((ext_vector_type(8)));
typedef float  f32x4   __attribute__((ext_vector_type(4)));
typedef float  f32x16  __attribute__((ext_vector_type(16)));

__device__ __forceinline__ unsigned f2bf2(float lo, float hi) {
    unsigned a = __float_as_uint(lo);
    unsigned b = __float_as_uint(hi);
    a += 0x7fffu + ((a >> 16) & 1u);
    b += 0x7fffu + ((b >> 16) & 1u);
    return (a >> 16) | (b & 0xffff0000u);
}

// ws layout (primary path):
//   qbf:  [BB][NP][CC] bf16        = 4 MiB
//   np2:  [NCH][BB][HW] f32        = 4 MiB
//   rn:   [BB][HW] f32             = 64 KiB
//   dotp: [4][BB][NP][HW] f32      = 16 MiB
//   feaP: [BB][CC/8][HW][8] bf16   = 64 MiB  (fragment-ready transposed fea)

// ---------------------------------------------------------------------------
// PRIMARY Kernel 1: prepT — stream fea once; emit bf16 fragment-layout feaP
// + exact fp32 ssq partials. No LDS, no barriers.
// grid = (NCH, BB), block = 256. Thread t owns k-columns {t+256m}.
// ---------------------------------------------------------------------------
__global__ __launch_bounds__(256) void prepT_kernel(const float* __restrict__ fea,
                                                    unsigned short* __restrict__ feaP,
                                                    float* __restrict__ np2) {
    int cch = blockIdx.x, b = blockIdx.y;
    int t = threadIdx.x;
    int c0 = cch * 32;

    const float* fb = fea + ((size_t)b * CC + c0) * HW + t;
    unsigned short* fp = feaP + (((size_t)b * 256 + (c0 >> 3)) * HW + t) * 8;

    float ssq[4] = {0.f, 0.f, 0.f, 0.f};

#pragma unroll
    for (int c8 = 0; c8 < 4; ++c8) {
#pragma unroll
        for (int m = 0; m < 4; ++m) {
            float v[8];
#pragma unroll
            for (int e = 0; e < 8; ++e)
                v[e] = fb[(size_t)(8 * c8 + e) * HW + 256 * m];
            float s = 0.f;
#pragma unroll
            for (int e = 0; e < 8; ++e) s += v[e] * v[e];
            ssq[m] += s;
            uint4 o;
            o.x = f2bf2(v[0], v[1]); o.y = f2bf2(v[2], v[3]);
            o.z = f2bf2(v[4], v[5]); o.w = f2bf2(v[6], v[7]);
            *(uint4*)&fp[((size_t)c8 * HW + 256 * m) * 8] = o;
        }
    }
#pragma unroll
    for (int m = 0; m < 4; ++m)
        np2[((size_t)cch * BB + b) * HW + t + 256 * m] = ssq[m];
}

// ---------------------------------------------------------------------------
// PRIMARY Kernel 2: qgather — queries are columns of feaP: 16B/thread copy.
// grid = (NP, BB), block = 256 (t = c8 page index).
// ---------------------------------------------------------------------------
__global__ __launch_bounds__(256) void qgather_kernel(const unsigned short* __restrict__ feaP,
                                                      const float* __restrict__ pl,
                                                      unsigned short* __restrict__ qbf) {
    int p = blockIdx.x, b = blockIdx.y, t = threadIdx.x;
    int ix = (int)(pl[2 * p + 0] * WW); ix = min(max(ix, 0), WW - 1);
    int iy = (int)(pl[2 * p + 1] * HH); iy = min(max(iy, 0), HH - 1);
    int kp = iy * WW + ix;
    uint4 v = *(const uint4*)&feaP[(((size_t)b * 256 + t) * HW + kp) * 8];
    *(uint4*)&qbf[((size_t)(b * NP + p)) * CC + 8 * t] = v;
}

// ---------------------------------------------------------------------------
// Kernel 3: nred — rn = rsqrt(sum of np2 pages). grid = (8, BB), block 128.
// ---------------------------------------------------------------------------
__global__ __launch_bounds__(128) void nred_kernel(const float* __restrict__ np2,
                                                   float* __restrict__ rn) {
    int b = blockIdx.y;
    int k = blockIdx.x * 128 + threadIdx.x;
    float s = 0.f;
#pragma unroll 8
    for (int cch = 0; cch < NCH; ++cch)
        s += np2[((size_t)cch * BB + b) * HW + k];
    rn[(size_t)b * HW + k] = rsqrtf(s);
}

// ---------------------------------------------------------------------------
// PRIMARY Kernel 4: LDS-free MFMA GEMM. A int4 from qbf, B int4 from feaP
// (wave reads a dense 1KB block), register double-buffer, no barriers.
// grid = (16*NCS, BB) XCD-chunk-swizzled, block 256; wave = (p32, k32) tile.
// ---------------------------------------------------------------------------
template<int NCS>
__global__ __launch_bounds__(256) void gemmf_kernel(const unsigned short* __restrict__ feaP,
                                                    const unsigned short* __restrict__ qbf,
                                                    float* __restrict__ dotp) {
    constexpr int CHALF = CC / NCS;
    constexpr int NST = CHALF / CT;
    constexpr int CSB = (NCS == 4) ? 2 : 1;

    int id = blockIdx.x + (int)gridDim.x * blockIdx.y;
    int cpx = (16 * NCS * BB) >> 3;
    int sid = (id & 7) * cpx + (id >> 3);
    int kc = sid & 15;
    int cs = (sid >> 4) & (NCS - 1);
    int b  = sid >> (4 + CSB);

    int t = threadIdx.x, lane = t & 63, w = t >> 6;
    int pt = w >> 1, kt = w & 1;
    int p0 = 32 * pt, k0 = KB * kc, c0 = cs * CHALF;
    int lo = lane & 31, hi = lane >> 5;

    const unsigned short* qb = qbf + ((size_t)(b * NP + p0 + lo)) * CC + c0 + 8 * hi;
    const unsigned short* fp = feaP + (((size_t)b * 256 + (c0 >> 3) + hi) * HW
                                       + k0 + 32 * kt + lo) * 8;

    f32x16 acc = {};
    union U { int4 i; bf16x8 v; };
    U a_cur[4], b_cur[4], a_nxt[4], b_nxt[4];

#pragma unroll
    for (int cw = 0; cw < 4; ++cw) {
        a_cur[cw].i = *(const int4*)(qb + 16 * cw);
        b_cur[cw].i = *(const int4*)(fp + (size_t)(2 * cw) * (HW * 8));
    }

    for (int s = 0; s < NST; ++s) {
        int sn = (s + 1 < NST) ? s + 1 : s;
#pragma unroll
        for (int cw = 0; cw < 4; ++cw) {
            a_nxt[cw].i = *(const int4*)(qb + sn * CT + 16 * cw);
            b_nxt[cw].i = *(const int4*)(fp + (size_t)(8 * sn + 2 * cw) * (HW * 8));
        }
#pragma unroll
        for (int cw = 0; cw < 4; ++cw)
            acc = __builtin_amdgcn_mfma_f32_32x32x16_bf16(a_cur[cw].v, b_cur[cw].v, acc, 0, 0, 0);
#pragma unroll
        for (int cw = 0; cw < 4; ++cw) { a_cur[cw] = a_nxt[cw]; b_cur[cw] = b_nxt[cw]; }
    }

    // D layout (32x32): col k = lane&31, row p = (r&3) + 8*(r>>2) + 4*hi
    float* dbase = dotp + (((size_t)cs * BB + b) * NP) * HW;
#pragma unroll
    for (int r = 0; r < 16; ++r) {
        int p = p0 + (r & 3) + 8 * (r >> 2) + 4 * hi;
        dbase[(size_t)p * HW + k0 + 32 * kt + lo] = acc[r];
    }
}

// ---------------------------------------------------------------------------
// FALLBACK Kernel 1: r8's prep (LDS extraction version), byte-identical.
// ---------------------------------------------------------------------------
__global__ __launch_bounds__(256) void prep_kernel(const float* __restrict__ fea,
                                                   const float* __restrict__ pl,
                                                   unsigned short* __restrict__ qbf,
                                                   float* __restrict__ np2) {
    int cch = blockIdx.x, b = blockIdx.y;
    int t = threadIdx.x, lane = t & 63, rr = t >> 6;

    int ix = (int)(pl[2 * lane + 0] * WW); ix = min(max(ix, 0), WW - 1);
    int iy = (int)(pl[2 * lane + 1] * HH); iy = min(max(iy, 0), HH - 1);
    int kp = iy * WW + ix;

    __shared__ unsigned short buf[2][4][HW];
    __shared__ unsigned short ex[NP][32 + 4];

    float ssq[16];
#pragma unroll
    for (int i = 0; i < 16; ++i) ssq[i] = 0.f;

    const float* base = fea + ((size_t)b * CC + cch * 32 + rr) * HW + 4 * lane;

#pragma unroll
    for (int ph = 0; ph < 8; ++ph) {
        float4 fv[4];
#pragma unroll
        for (int s = 0; s < 4; ++s)
            fv[s] = *(const float4*)(base + (size_t)(ph * 4) * HW + 256 * s);
#pragma unroll
        for (int s = 0; s < 4; ++s) {
            ssq[4 * s + 0] += fv[s].x * fv[s].x;
            ssq[4 * s + 1] += fv[s].y * fv[s].y;
            ssq[4 * s + 2] += fv[s].z * fv[s].z;
            ssq[4 * s + 3] += fv[s].w * fv[s].w;
            uint2 pk;
            pk.x = f2bf2(fv[s].x, fv[s].y);
            pk.y = f2bf2(fv[s].z, fv[s].w);
            *(uint2*)&buf[ph & 1][rr][4 * lane + 256 * s] = pk;
        }
        __syncthreads();
        ex[lane][ph * 4 + rr] = buf[ph & 1][rr][kp];
    }
    __syncthreads();

    float* red = (float*)buf;
#pragma unroll
    for (int s = 0; s < 4; ++s) {
        f32x4 v = {ssq[4 * s + 0], ssq[4 * s + 1], ssq[4 * s + 2], ssq[4 * s + 3]};
        *(f32x4*)&red[rr * HW + 4 * lane + 256 * s] = v;
    }
    __syncthreads();
    {
        int k0 = 4 * t;
        f32x4 r0 = *(f32x4*)&red[0 * HW + k0];
        f32x4 r1 = *(f32x4*)&red[1 * HW + k0];
        f32x4 r2 = *(f32x4*)&red[2 * HW + k0];
        f32x4 r3 = *(f32x4*)&red[3 * HW + k0];
        f32x4 sum = (r0 + r1) + (r2 + r3);
        *(f32x4*)&np2[((size_t)cch * BB + b) * HW + k0] = sum;
    }
    {
        int p = t >> 2, part = t & 3;
        uint2 lo = *(uint2*)&ex[p][8 * part];
        uint2 hi = *(uint2*)&ex[p][8 * part + 4];
        uint4 o = make_uint4(lo.x, lo.y, hi.x, hi.y);
        *(uint4*)&qbf[((size_t)(b * NP + p)) * CC + cch * 32 + 8 * part] = o;
    }
}

// ---------------------------------------------------------------------------
// FALLBACK Kernel 4: r8's LDS gemm (NCS=2), byte-identical.
// ---------------------------------------------------------------------------
__global__ __launch_bounds__(256) void gemm_lds_kernel(const float* __restrict__ fea,
                                                       const unsigned short* __restrict__ qbf,
                                                       float* __restrict__ dotp) {
    constexpr int NCS = 2, CHALF = CC / 2, NST = CHALF / CT;
    int id = blockIdx.x + (int)gridDim.x * blockIdx.y;
    int cpx = (16 * NCS * BB) >> 3;
    int sid = (id & 7) * cpx + (id >> 3);
    int kc = sid & 15, cs = (sid >> 4) & 1, b = sid >> 5;

    int t = threadIdx.x, lane = t & 63, w = t >> 6;
    int pt = w >> 1, kt = w & 1;
    int p0 = 32 * pt, k0 = KB * kc, c0 = cs * CHALF;
    int lo = lane & 31, hi = lane >> 5;

    __shared__ __align__(16) unsigned short bt[2][CT][BP];

    int sc = t >> 2, sq = t & 3;
    const float* gsrc = fea + ((size_t)b * CC + c0 + sc) * HW + k0 + 16 * sq;
    const unsigned short* qb = qbf + ((size_t)(b * NP + p0 + lo)) * CC + c0 + 8 * hi;

    f32x16 acc = {};
    union UA { int4 i; bf16x8 v; };

    float4 g[4];
#pragma unroll
    for (int h = 0; h < 4; ++h) g[h] = *(const float4*)(gsrc + 4 * h);
    UA a_cur[4], a_nxt[4];
#pragma unroll
    for (int cw = 0; cw < 4; ++cw) a_cur[cw].i = *(const int4*)(qb + 16 * cw);

    for (int s = 0; s < NST; ++s) {
        int cur = s & 1;
#pragma unroll
        for (int h = 0; h < 4; ++h) {
            uint2 pk;
            pk.x = f2bf2(g[h].x, g[h].y);
            pk.y = f2bf2(g[h].z, g[h].w);
            *(uint2*)&bt[cur][sc][16 * sq + 4 * h] = pk;
        }
        __syncthreads();
        int sn = (s + 1 < NST) ? s + 1 : s;
#pragma unroll
        for (int h = 0; h < 4; ++h)
            g[h] = *(const float4*)(gsrc + (size_t)sn * CT * HW + 4 * h);
#pragma unroll
        for (int cw = 0; cw < 4; ++cw)
            a_nxt[cw].i = *(const int4*)(qb + (size_t)sn * CT + 16 * cw);
#pragma unroll
        for (int cw = 0; cw < 4; ++cw) {
            union { unsigned short u[8]; bf16x8 v; } bf;
#pragma unroll
            for (int e = 0; e < 8; ++e)
                bf.u[e] = bt[cur][16 * cw + 8 * hi + e][32 * kt + lo];
            acc = __builtin_amdgcn_mfma_f32_32x32x16_bf16(a_cur[cw].v, bf.v, acc, 0, 0, 0);
        }
#pragma unroll
        for (int cw = 0; cw < 4; ++cw) a_cur[cw] = a_nxt[cw];
    }

    float* dbase = dotp + (((size_t)cs * BB + b) * NP) * HW;
#pragma unroll
    for (int r = 0; r < 16; ++r) {
        int p = p0 + (r & 3) + 8 * (r >> 2) + 4 * hi;
        dbase[(size_t)p * HW + k0 + 32 * kt + lo] = acc[r];
    }
}

// ---------------------------------------------------------------------------
// Kernel 5: finalize (templated over NCS).
// ---------------------------------------------------------------------------
template<int NCS>
__global__ __launch_bounds__(256) void finalize_kernel(const float* __restrict__ dotp,
                                                       const float* __restrict__ rn,
                                                       const float* __restrict__ pl,
                                                       const int* __restrict__ valid,
                                                       float* __restrict__ out) {
    int p = blockIdx.x, b = blockIdx.y;
    int t = threadIdx.x;
    int k0 = 4 * t;

    int ix = (int)(pl[2 * p + 0] * WW); ix = min(max(ix, 0), WW - 1);
    int iy = (int)(pl[2 * p + 1] * HH); iy = min(max(iy, 0), HH - 1);
    int kp = iy * WW + ix;
    float rnp = rn[(size_t)b * HW + kp];

    f32x4 d = {0.f, 0.f, 0.f, 0.f};
#pragma unroll
    for (int cs = 0; cs < NCS; ++cs)
        d += *(const f32x4*)(dotp + (((size_t)cs * BB + b) * NP + p) * HW + k0);
    float4 rk = *(const float4*)&rn[(size_t)b * HW + k0];

    float val[4];
    val[0] = d[0] * rk.x * rnp;
    val[1] = d[1] * rk.y * rnp;
    val[2] = d[2] * rk.z * rnp;
    val[3] = d[3] * rk.w * rnp;

    float mn = fminf(fminf(val[0], val[1]), fminf(val[2], val[3]));
    float mx = fmaxf(fmaxf(val[0], val[1]), fmaxf(val[2], val[3]));
#pragma unroll
    for (int off = 32; off; off >>= 1) {
        mn = fminf(mn, __shfl_xor(mn, off));
        mx = fmaxf(mx, __shfl_xor(mx, off));
    }
    __shared__ float smn[4], smx[4];
    int wave = t >> 6;
    if ((t & 63) == 0) { smn[wave] = mn; smx[wave] = mx; }
    __syncthreads();
    mn = fminf(fminf(smn[0], smn[1]), fminf(smn[2], smn[3]));
    mx = fmaxf(fmaxf(smx[0], smx[1]), fmaxf(smx[2], smx[3]));

    bool vld = valid[p] != 0;
    float4 o;
    o.x = vld ? (val[0] - mn) / mx : 0.f;
    o.y = vld ? (val[1] - mn) / mx : 0.f;
    o.z = vld ? (val[2] - mn) / mx : 0.f;
    o.w = vld ? (val[3] - mn) / mx : 0.f;
    *(float4*)&out[((size_t)(b * NP + p)) * HW + k0] = o;
}

// ---------------------------------------------------------------------------
extern "C" void kernel_launch(void* const* d_in, const int* in_sizes, int n_in,
                              void* d_out, int out_size, void* d_ws, size_t ws_size,
                              hipStream_t stream) {
    const float* fea = (const float*)d_in[0];
    const float* pl  = (const float*)d_in[1];
    const int* valid = (const int*)d_in[2];
    float* out = (float*)d_out;

    unsigned short* qbf = (unsigned short*)d_ws;                     // 4 MiB
    float* np2 = (float*)(qbf + (size_t)BB * NP * CC);               // 4 MiB
    float* rn  = np2 + (size_t)NCH * BB * HW;                        // 64 KiB
    float* dotp = rn + (size_t)BB * HW;                              // up to 16 MiB
    unsigned short* feaP = (unsigned short*)(dotp + (size_t)4 * BB * NP * HW); // 64 MiB

    const size_t needP = (size_t)BB * NP * CC * 2                    // qbf
                       + ((size_t)NCH * BB * HW + (size_t)BB * HW) * 4
                       + (size_t)4 * BB * NP * HW * 4                // dotp NCS=4
                       + (size_t)BB * (CC / 8) * HW * 8 * 2;         // feaP

    if (ws_size >= needP) {
        prepT_kernel<<<dim3(NCH, BB), 256, 0, stream>>>(fea, feaP, np2);
        qgather_kernel<<<dim3(NP, BB), 256, 0, stream>>>(feaP, pl, qbf);
        nred_kernel<<<dim3(8, BB), 128, 0, stream>>>(np2, rn);
        gemmf_kernel<4><<<dim3(64, BB), 256, 0, stream>>>(feaP, qbf, dotp);
        finalize_kernel<4><<<dim3(NP, BB), 256, 0, stream>>>(dotp, rn, pl, valid, out);
    } else {
        prep_kernel<<<dim3(NCH, BB), 256, 0, stream>>>(fea, pl, qbf, np2);
        nred_kernel<<<dim3(8, BB), 128, 0, stream>>>(np2, rn);
        gemm_lds_kernel<<<dim3(32, BB), 256, 0, stream>>>(fea, qbf, dotp);
        finalize_kernel<2><<<dim3(NP, BB), 256, 0, stream>>>(dotp, rn, pl, valid, out);
    }
}

// Round 11
// 63.313 us; speedup vs baseline: 2.8788x; 1.1406x over previous
//
#include <hip/hip_runtime.h>

// Problem constants
#define BB 16
#define CC 2048
#define HH 32
#define WW 32
#define HW 1024   // H*W
#define NP 64     // n_points

#define PCH 32            // c-rows per prep block
#define NCH (CC/PCH)      // 64 chunks
#define KB 64             // spatial-k per gemm block (2 k32-tiles)
#define CT 64             // c per K-step
#define NCS 2             // c-split
#define CHALF (CC/NCS)    // 1024
#define NST (CHALF/CT)    // 16
#define BP 68             // LDS k-pitch in u16

typedef __bf16 bf16x8  __attribute__((ext_vector_type(8)));
typedef float  f32x4   __attribute__((ext_vector_type(4)));
typedef float  f32x16  __attribute__((ext_vector_type(16)));

__device__ __forceinline__ unsigned f2bf2(float lo, float hi) {
    unsigned a = __float_as_uint(lo);
    unsigned b = __float_as_uint(hi);
    a += 0x7fffu + ((a >> 16) & 1u);
    b += 0x7fffu + ((b >> 16) & 1u);
    return (a >> 16) | (b & 0xffff0000u);
}

// ws layout:
//   qbf:  [BB][NP][CC] bf16        = 4 MiB
//   np2:  [NCH][BB][HW] f32        = 4 MiB
//   rn:   [BB][HW] f32             = 64 KiB
//   dotp: [NCS][BB][NP][HW] f32    = 8 MiB
//   fb16: [BB][CC][HW] bf16        = 64 MiB   (bf16 cast of fea; primary only)

// ---------------------------------------------------------------------------
// Kernel 1: prep. r8's proven scan (ssq + LDS query extraction) + optional
// coalesced fb16 (bf16 fea) write. grid (NCH, BB), block 256.
// ---------------------------------------------------------------------------
template<bool WRITE_FB16>
__global__ __launch_bounds__(256) void prep_kernel(const float* __restrict__ fea,
                                                   const float* __restrict__ pl,
                                                   unsigned short* __restrict__ qbf,
                                                   float* __restrict__ np2,
                                                   unsigned short* __restrict__ fb16) {
    int cch = blockIdx.x, b = blockIdx.y;
    int t = threadIdx.x, lane = t & 63, rr = t >> 6;

    int ix = (int)(pl[2 * lane + 0] * WW); ix = min(max(ix, 0), WW - 1);
    int iy = (int)(pl[2 * lane + 1] * HH); iy = min(max(iy, 0), HH - 1);
    int kp = iy * WW + ix;

    __shared__ unsigned short buf[2][4][HW];
    __shared__ unsigned short ex[NP][PCH + 4];

    float ssq[16];
#pragma unroll
    for (int i = 0; i < 16; ++i) ssq[i] = 0.f;

    const float* base = fea + ((size_t)b * CC + cch * PCH + rr) * HW + 4 * lane;

#pragma unroll
    for (int ph = 0; ph < PCH / 4; ++ph) {
        float4 fv[4];
#pragma unroll
        for (int s = 0; s < 4; ++s)
            fv[s] = *(const float4*)(base + (size_t)(ph * 4) * HW + 256 * s);
#pragma unroll
        for (int s = 0; s < 4; ++s) {
            ssq[4 * s + 0] += fv[s].x * fv[s].x;
            ssq[4 * s + 1] += fv[s].y * fv[s].y;
            ssq[4 * s + 2] += fv[s].z * fv[s].z;
            ssq[4 * s + 3] += fv[s].w * fv[s].w;
            uint2 pk;
            pk.x = f2bf2(fv[s].x, fv[s].y);
            pk.y = f2bf2(fv[s].z, fv[s].w);
            *(uint2*)&buf[ph & 1][rr][4 * lane + 256 * s] = pk;
            if (WRITE_FB16) {
                *(uint2*)&fb16[((size_t)b * CC + cch * PCH + ph * 4 + rr) * HW
                               + 4 * lane + 256 * s] = pk;
            }
        }
        __syncthreads();
        ex[lane][ph * 4 + rr] = buf[ph & 1][rr][kp];
    }
    __syncthreads();

    float* red = (float*)buf;
#pragma unroll
    for (int s = 0; s < 4; ++s) {
        f32x4 v = {ssq[4 * s + 0], ssq[4 * s + 1], ssq[4 * s + 2], ssq[4 * s + 3]};
        *(f32x4*)&red[rr * HW + 4 * lane + 256 * s] = v;
    }
    __syncthreads();
    {
        int k0 = 4 * t;
        f32x4 r0 = *(f32x4*)&red[0 * HW + k0];
        f32x4 r1 = *(f32x4*)&red[1 * HW + k0];
        f32x4 r2 = *(f32x4*)&red[2 * HW + k0];
        f32x4 r3 = *(f32x4*)&red[3 * HW + k0];
        f32x4 sum = (r0 + r1) + (r2 + r3);
        *(f32x4*)&np2[((size_t)cch * BB + b) * HW + k0] = sum;
    }
    {
        int p = t >> 2, part = t & 3;
        uint2 lo = *(uint2*)&ex[p][8 * part];
        uint2 hi = *(uint2*)&ex[p][8 * part + 4];
        uint4 o = make_uint4(lo.x, lo.y, hi.x, hi.y);
        *(uint4*)&qbf[((size_t)(b * NP + p)) * CC + cch * PCH + 8 * part] = o;
    }
}

// ---------------------------------------------------------------------------
// Kernel 2: nred. grid (8, BB), block 128.
// ---------------------------------------------------------------------------
__global__ __launch_bounds__(128) void nred_kernel(const float* __restrict__ np2,
                                                   float* __restrict__ rn) {
    int b = blockIdx.y;
    int k = blockIdx.x * 128 + threadIdx.x;
    float s = 0.f;
#pragma unroll 8
    for (int cch = 0; cch < NCH; ++cch)
        s += np2[((size_t)cch * BB + b) * HW + k];
    rn[(size_t)b * HW + k] = rsqrtf(s);
}

// ---------------------------------------------------------------------------
// PRIMARY Kernel 3: gemm from bf16 fb16. r8's structure (NCS=2, 32x32x16,
// BP=68 tile, A-prefetch, single barrier/step, double buffer) but staging
// loads are uint4 bf16 (half the staging bytes, no f2bf2 in the loop).
// grid (16*NCS, BB) XCD-chunk-swizzled, block 256.
// ---------------------------------------------------------------------------
__global__ __launch_bounds__(256) void gemm_bf_kernel(const unsigned short* __restrict__ fb16,
                                                      const unsigned short* __restrict__ qbf,
                                                      float* __restrict__ dotp) {
    int id = blockIdx.x + (int)gridDim.x * blockIdx.y;
    int cpx = (16 * NCS * BB) >> 3;
    int sid = (id & 7) * cpx + (id >> 3);
    int kc = sid & 15, cs = (sid >> 4) & 1, b = sid >> 5;

    int t = threadIdx.x, lane = t & 63, w = t >> 6;
    int pt = w >> 1, kt = w & 1;
    int p0 = 32 * pt, k0 = KB * kc, c0 = cs * CHALF;
    int lo = lane & 31, hi = lane >> 5;

    __shared__ __align__(16) unsigned short bt[2][CT][BP];

    // staging: thread -> c-row sc (0..63), k-octet kq (0..3): k = 8kq & 32+8kq
    int sc = t >> 2, kq = t & 3;
    const unsigned short* gsrc = fb16 + ((size_t)b * CC + c0 + sc) * HW + k0 + 8 * kq;

    const unsigned short* qb = qbf + ((size_t)(b * NP + p0 + lo)) * CC + c0 + 8 * hi;

    f32x16 acc = {};
    union UA { int4 i; bf16x8 v; };

    // preload step 0
    uint4 g0 = *(const uint4*)(gsrc);
    uint4 g1 = *(const uint4*)(gsrc + 32);
    UA a_cur[4], a_nxt[4];
#pragma unroll
    for (int cw = 0; cw < 4; ++cw) a_cur[cw].i = *(const int4*)(qb + 16 * cw);

    for (int s = 0; s < NST; ++s) {
        int cur = s & 1;
        *(uint4*)&bt[cur][sc][8 * kq]      = g0;
        *(uint4*)&bt[cur][sc][32 + 8 * kq] = g1;
        __syncthreads();

        int sn = (s + 1 < NST) ? s + 1 : s;
        g0 = *(const uint4*)(gsrc + (size_t)sn * CT * HW);
        g1 = *(const uint4*)(gsrc + (size_t)sn * CT * HW + 32);
#pragma unroll
        for (int cw = 0; cw < 4; ++cw)
            a_nxt[cw].i = *(const int4*)(qb + (size_t)sn * CT + 16 * cw);

#pragma unroll
        for (int cw = 0; cw < 4; ++cw) {
            union { unsigned short u[8]; bf16x8 v; } bf;
#pragma unroll
            for (int e = 0; e < 8; ++e)
                bf.u[e] = bt[cur][16 * cw + 8 * hi + e][32 * kt + lo];
            acc = __builtin_amdgcn_mfma_f32_32x32x16_bf16(a_cur[cw].v, bf.v, acc, 0, 0, 0);
        }
#pragma unroll
        for (int cw = 0; cw < 4; ++cw) a_cur[cw] = a_nxt[cw];
    }

    float* dbase = dotp + (((size_t)cs * BB + b) * NP) * HW;
#pragma unroll
    for (int r = 0; r < 16; ++r) {
        int p = p0 + (r & 3) + 8 * (r >> 2) + 4 * hi;
        dbase[(size_t)p * HW + k0 + 32 * kt + lo] = acc[r];
    }
}

// ---------------------------------------------------------------------------
// FALLBACK Kernel 3: r8's fp32-staging gemm (NCS=2), byte-identical.
// ---------------------------------------------------------------------------
__global__ __launch_bounds__(256) void gemm_lds_kernel(const float* __restrict__ fea,
                                                       const unsigned short* __restrict__ qbf,
                                                       float* __restrict__ dotp) {
    int id = blockIdx.x + (int)gridDim.x * blockIdx.y;
    int cpx = (16 * NCS * BB) >> 3;
    int sid = (id & 7) * cpx + (id >> 3);
    int kc = sid & 15, cs = (sid >> 4) & 1, b = sid >> 5;

    int t = threadIdx.x, lane = t & 63, w = t >> 6;
    int pt = w >> 1, kt = w & 1;
    int p0 = 32 * pt, k0 = KB * kc, c0 = cs * CHALF;
    int lo = lane & 31, hi = lane >> 5;

    __shared__ __align__(16) unsigned short bt[2][CT][BP];

    int sc = t >> 2, sq = t & 3;
    const float* gsrc = fea + ((size_t)b * CC + c0 + sc) * HW + k0 + 16 * sq;
    const unsigned short* qb = qbf + ((size_t)(b * NP + p0 + lo)) * CC + c0 + 8 * hi;

    f32x16 acc = {};
    union UA { int4 i; bf16x8 v; };

    float4 g[4];
#pragma unroll
    for (int h = 0; h < 4; ++h) g[h] = *(const float4*)(gsrc + 4 * h);
    UA a_cur[4], a_nxt[4];
#pragma unroll
    for (int cw = 0; cw < 4; ++cw) a_cur[cw].i = *(const int4*)(qb + 16 * cw);

    for (int s = 0; s < NST; ++s) {
        int cur = s & 1;
#pragma unroll
        for (int h = 0; h < 4; ++h) {
            uint2 pk;
            pk.x = f2bf2(g[h].x, g[h].y);
            pk.y = f2bf2(g[h].z, g[h].w);
            *(uint2*)&bt[cur][sc][16 * sq + 4 * h] = pk;
        }
        __syncthreads();
        int sn = (s + 1 < NST) ? s + 1 : s;
#pragma unroll
        for (int h = 0; h < 4; ++h)
            g[h] = *(const float4*)(gsrc + (size_t)sn * CT * HW + 4 * h);
#pragma unroll
        for (int cw = 0; cw < 4; ++cw)
            a_nxt[cw].i = *(const int4*)(qb + (size_t)sn * CT + 16 * cw);
#pragma unroll
        for (int cw = 0; cw < 4; ++cw) {
            union { unsigned short u[8]; bf16x8 v; } bf;
#pragma unroll
            for (int e = 0; e < 8; ++e)
                bf.u[e] = bt[cur][16 * cw + 8 * hi + e][32 * kt + lo];
            acc = __builtin_amdgcn_mfma_f32_32x32x16_bf16(a_cur[cw].v, bf.v, acc, 0, 0, 0);
        }
#pragma unroll
        for (int cw = 0; cw < 4; ++cw) a_cur[cw] = a_nxt[cw];
    }

    float* dbase = dotp + (((size_t)cs * BB + b) * NP) * HW;
#pragma unroll
    for (int r = 0; r < 16; ++r) {
        int p = p0 + (r & 3) + 8 * (r >> 2) + 4 * hi;
        dbase[(size_t)p * HW + k0 + 32 * kt + lo] = acc[r];
    }
}

// ---------------------------------------------------------------------------
// Kernel 4: finalize (NCS=2). grid (NP, BB), block 256.
// ---------------------------------------------------------------------------
__global__ __launch_bounds__(256) void finalize_kernel(const float* __restrict__ dotp,
                                                       const float* __restrict__ rn,
                                                       const float* __restrict__ pl,
                                                       const int* __restrict__ valid,
                                                       float* __restrict__ out) {
    int p = blockIdx.x, b = blockIdx.y;
    int t = threadIdx.x;
    int k0 = 4 * t;

    int ix = (int)(pl[2 * p + 0] * WW); ix = min(max(ix, 0), WW - 1);
    int iy = (int)(pl[2 * p + 1] * HH); iy = min(max(iy, 0), HH - 1);
    int kp = iy * WW + ix;
    float rnp = rn[(size_t)b * HW + kp];

    f32x4 d = {0.f, 0.f, 0.f, 0.f};
#pragma unroll
    for (int cs = 0; cs < NCS; ++cs)
        d += *(const f32x4*)(dotp + (((size_t)cs * BB + b) * NP + p) * HW + k0);
    float4 rk = *(const float4*)&rn[(size_t)b * HW + k0];

    float val[4];
    val[0] = d[0] * rk.x * rnp;
    val[1] = d[1] * rk.y * rnp;
    val[2] = d[2] * rk.z * rnp;
    val[3] = d[3] * rk.w * rnp;

    float mn = fminf(fminf(val[0], val[1]), fminf(val[2], val[3]));
    float mx = fmaxf(fmaxf(val[0], val[1]), fmaxf(val[2], val[3]));
#pragma unroll
    for (int off = 32; off; off >>= 1) {
        mn = fminf(mn, __shfl_xor(mn, off));
        mx = fmaxf(mx, __shfl_xor(mx, off));
    }
    __shared__ float smn[4], smx[4];
    int wave = t >> 6;
    if ((t & 63) == 0) { smn[wave] = mn; smx[wave] = mx; }
    __syncthreads();
    mn = fminf(fminf(smn[0], smn[1]), fminf(smn[2], smn[3]));
    mx = fmaxf(fmaxf(smx[0], smx[1]), fmaxf(smx[2], smx[3]));

    bool vld = valid[p] != 0;
    float4 o;
    o.x = vld ? (val[0] - mn) / mx : 0.f;
    o.y = vld ? (val[1] - mn) / mx : 0.f;
    o.z = vld ? (val[2] - mn) / mx : 0.f;
    o.w = vld ? (val[3] - mn) / mx : 0.f;
    *(float4*)&out[((size_t)(b * NP + p)) * HW + k0] = o;
}

// ---------------------------------------------------------------------------
extern "C" void kernel_launch(void* const* d_in, const int* in_sizes, int n_in,
                              void* d_out, int out_size, void* d_ws, size_t ws_size,
                              hipStream_t stream) {
    const float* fea = (const float*)d_in[0];
    const float* pl  = (const float*)d_in[1];
    const int* valid = (const int*)d_in[2];
    float* out = (float*)d_out;

    unsigned short* qbf = (unsigned short*)d_ws;                     // 4 MiB
    float* np2 = (float*)(qbf + (size_t)BB * NP * CC);               // 4 MiB
    float* rn  = np2 + (size_t)NCH * BB * HW;                        // 64 KiB
    float* dotp = rn + (size_t)BB * HW;                              // 8 MiB
    unsigned short* fb16 = (unsigned short*)(dotp + (size_t)NCS * BB * NP * HW); // 64 MiB

    const size_t need = (size_t)BB * NP * CC * 2
                      + ((size_t)NCH * BB * HW + (size_t)BB * HW) * 4
                      + (size_t)NCS * BB * NP * HW * 4
                      + (size_t)BB * CC * HW * 2;                    // = 83,951,616 B

    if (ws_size >= need) {
        // PRIMARY: bf16 second pass.
        prep_kernel<true><<<dim3(NCH, BB), 256, 0, stream>>>(fea, pl, qbf, np2, fb16);
        nred_kernel<<<dim3(8, BB), 128, 0, stream>>>(np2, rn);
        gemm_bf_kernel<<<dim3(16 * NCS, BB), 256, 0, stream>>>(fb16, qbf, dotp);
        finalize_kernel<<<dim3(NP, BB), 256, 0, stream>>>(dotp, rn, pl, valid, out);
    } else {
        // FALLBACK: r8 path; gemm deliberately run 2x (idempotent) as a
        // timing marker to disambiguate which branch executed (~+30 us).
        prep_kernel<false><<<dim3(NCH, BB), 256, 0, stream>>>(fea, pl, qbf, np2, nullptr);
        nred_kernel<<<dim3(8, BB), 128, 0, stream>>>(np2, rn);
        gemm_lds_kernel<<<dim3(16 * NCS, BB), 256, 0, stream>>>(fea, qbf, dotp);
        gemm_lds_kernel<<<dim3(16 * NCS, BB), 256, 0, stream>>>(fea, qbf, dotp);
        finalize_kernel<<<dim3(NP, BB), 256, 0, stream>>>(dotp, rn, pl, valid, out);
    }
}